// Round 15
// baseline (974.501 us; speedup 1.0000x reference)
//
#include <hip/hip_runtime.h>
#include <math.h>

#define NN 20000
#define EE 100000
#define FIN 167
#define KP1 192    // layer-1 K padded to mult of 32
#define HID 1024   // H*O = 4*256
#define OO 256
#define NB 16      // nodes per k_gath block

typedef unsigned short u16;
typedef short bf16x8 __attribute__((ext_vector_type(8)));
typedef float f32x4  __attribute__((ext_vector_type(4)));

__device__ __forceinline__ float bf(u16 u){ return __uint_as_float(((unsigned)u)<<16); }
__device__ __forceinline__ u16 fb(float v){            // f32 -> bf16 RNE
  unsigned u = __float_as_uint(v);
  return (u16)((u + 0x7FFFu + ((u>>16)&1u)) >> 16);
}
__device__ __forceinline__ float ldv(const float* p, long i){ return p[i]; }
__device__ __forceinline__ float ldv(const u16*   p, long i){ return bf(p[i]); }

// ---------------- CSR build ----------------
__global__ void k_count(const int* __restrict__ ei, int* __restrict__ counts){
  int e = blockIdx.x*256 + threadIdx.x;
  if (e < EE) atomicAdd(&counts[ei[EE+e]], 1);
}

__global__ __launch_bounds__(256) void k_scan(const int* __restrict__ counts, int* __restrict__ iptr){
  __shared__ int sd[256];
  int tid = threadIdx.x;
  int carry = 0;
  for (int base=0; base<NN; base+=256){
    int i = base+tid;
    int v = (i<NN)? counts[i] : 0;
    sd[tid]=v;
    __syncthreads();
    for (int off=1; off<256; off<<=1){
      int t = (tid>=off)? sd[tid-off] : 0;
      __syncthreads();
      sd[tid] += t;
      __syncthreads();
    }
    if (i<NN) iptr[i] = carry + sd[tid] - v;
    carry += sd[255];
    __syncthreads();
  }
  if (tid==0) iptr[NN]=carry;
}

__global__ void k_fill(const int* __restrict__ ei, const int* __restrict__ iptr,
                       int* __restrict__ cursor, int* __restrict__ eid){
  int e = blockIdx.x*256 + threadIdx.x;
  if (e < EE){
    int d = ei[EE+e];
    int pos = atomicAdd(&cursor[d],1);
    eid[iptr[d]+pos] = e;
  }
}

// ---------------- BatchNorm stats ----------------
template<typename T>
__global__ void k_bnstats(const T* __restrict__ X, float* __restrict__ sums, int F){
  int f = blockIdx.y*256 + threadIdx.x;
  if (f >= F) return;
  int r0 = blockIdx.x*100, r1 = r0+100;
  float s=0.f, s2=0.f;
  for (int r=r0;r<r1;r++){ float v = ldv(X,(long)r*F+f); s += v; s2 += v*v; }
  atomicAdd(&sums[f], s);
  atomicAdd(&sums[F+f], s2);
}

__global__ void k_bnfin(const float* __restrict__ sums, const float* __restrict__ g,
                        const float* __restrict__ b, float* __restrict__ scale,
                        float* __restrict__ shift, int F){
  int f = blockIdx.x*256 + threadIdx.x;
  if (f >= F) return;
  float mu  = sums[f]   * (1.f/NN);
  float var = sums[F+f] * (1.f/NN) - mu*mu;
  float sc  = rsqrtf(var + 1e-5f) * g[f];
  scale[f] = sc;
  shift[f] = b[f] - mu*sc;
}

// ---------------- BN-folded fused weight prep ----------------
__global__ __launch_bounds__(256) void k_foldT(const float* __restrict__ Wg, const float* __restrict__ Wl,
                        const float* __restrict__ scale,
                        u16* __restrict__ Wt, int K, int Kp){
  __shared__ float t[32][33];
  int k0 = blockIdx.x*32, c0 = blockIdx.y*32;
  int tx = threadIdx.x & 31, ty = threadIdx.x >> 5;
  bool second = (c0 >= HID);
  const float* W = second ? Wl : Wg;
  int cc0 = second ? c0 - HID : c0;
  #pragma unroll
  for (int i=0;i<4;i++){
    int k = k0 + ty + i*8;
    t[ty+i*8][tx] = (k < K) ? W[(long)k*HID + cc0 + tx] * scale[k] : 0.f;
  }
  __syncthreads();
  #pragma unroll
  for (int i=0;i<4;i++){
    int c = c0 + ty + i*8;
    Wt[(long)c*Kp + k0 + tx] = fb(t[tx][ty+i*8]);
  }
}

// cst init: lb for lin half, 0 for hg half
__global__ void k_cinit(const float* __restrict__ lb, float* __restrict__ cst){
  int c = blockIdx.x*256 + threadIdx.x;
  if (c < 2*HID) cst[c] = (c >= HID) ? lb[c-HID] : 0.f;
}

// cst[c] += sum_k shift[k]*W[k][c]  — parallel reduction, coalesced
__global__ __launch_bounds__(256) void k_const(const float* __restrict__ Wg, const float* __restrict__ Wl,
                        const float* __restrict__ shift, float* __restrict__ cst, int K){
  int tx = threadIdx.x & 63, ty = threadIdx.x >> 6;
  int c = blockIdx.x*64 + tx;
  bool second = c >= HID;
  const float* W = second ? Wl : Wg;
  int cc = second ? c-HID : c;
  int k0 = blockIdx.y*128;
  int k1 = min(K, k0+128);
  float s = 0.f;
  for (int k=k0+ty; k<k1; k+=4) s += shift[k]*W[(long)k*HID+cc];
  __shared__ float red[256];
  red[threadIdx.x] = s;
  __syncthreads();
  if (ty == 0){
    float tot = red[tx] + red[tx+64] + red[tx+128] + red[tx+192];
    atomicAdd(&cst[c], tot);
  }
}

__global__ void k_cast(const float* __restrict__ x, u16* __restrict__ xb){
  long idx = (long)blockIdx.x*256 + threadIdx.x;
  if (idx >= (long)NN*KP1) return;
  int n = (int)(idx / KP1), k = (int)(idx % KP1);
  xb[idx] = (k<FIN)? fb(x[(long)n*FIN+k]) : (u16)0;
}

__global__ void k_we16(const float* __restrict__ We, u16* __restrict__ We16){
  int i = blockIdx.x*256 + threadIdx.x;
  if (i < 10*HID) We16[i] = fb(We[i]);
}

// ---------------- LDS-tiled MFMA GEMM with global_load_lds staging ----------------
// Tile 128x128, BK=32. Each 8KB buffer = 128 rows x 64B. One global_load_lds
// stages 64 lanes x 16B = 16 rows; each wave issues TWO per buffer (rows 32w..32w+31).
// LDS dest is wave-uniform base + lane*16B: lane i -> row i>>2, chunk i&3 = byte i*16.
__global__ __launch_bounds__(256) void k_gemm(const u16* __restrict__ A, int K,
                     const u16* __restrict__ Wt, const float* __restrict__ cst,
                     u16* __restrict__ Chg, u16* __restrict__ Clin){
  __shared__ u16 As[128*32];   // [row][k] contiguous, 64 B/row
  __shared__ u16 Bs[128*32];
  int tid = threadIdx.x;
  int wave = tid>>6, lane = tid&63, quad = lane>>4, lo = lane&15;
  int wr = wave>>1, wc = wave&1;
  int row0 = blockIdx.y*128;
  int col0 = blockIdx.x*128;
  // staging: wave w covers rows [32w, 32w+32): two instructions, 16 rows each
  int ra0 = wave*32 + (lane>>2);
  int ra1 = ra0 + 16;
  int qa = lane&3;
  int gr0 = row0 + ra0; if (gr0 >= NN) gr0 = NN-1;   // clamp: garbage rows never stored
  int gr1 = row0 + ra1; if (gr1 >= NN) gr1 = NN-1;
  const u16* Agp0 = A  + (long)gr0*K + qa*8;
  const u16* Agp1 = A  + (long)gr1*K + qa*8;
  const u16* Bgp0 = Wt + (long)(col0+ra0)*K + qa*8;
  const u16* Bgp1 = Wt + (long)(col0+ra1)*K + qa*8;
  u16* AsW0 = &As[wave*1024];            // rows 32w..32w+15
  u16* AsW1 = &As[wave*1024 + 512];      // rows 32w+16..32w+31
  u16* BsW0 = &Bs[wave*1024];
  u16* BsW1 = &Bs[wave*1024 + 512];
  f32x4 acc[4][4] = {};
  for (int k0=0;k0<K;k0+=32){
    __builtin_amdgcn_global_load_lds(Agp0 + k0, AsW0, 16, 0, 0);
    __builtin_amdgcn_global_load_lds(Agp1 + k0, AsW1, 16, 0, 0);
    __builtin_amdgcn_global_load_lds(Bgp0 + k0, BsW0, 16, 0, 0);
    __builtin_amdgcn_global_load_lds(Bgp1 + k0, BsW1, 16, 0, 0);
    __syncthreads();   // compiler emits vmcnt(0) drain before barrier
    bf16x8 af[4], bg[4];
    #pragma unroll
    for (int i=0;i<4;i++) af[i] = *(const bf16x8*)&As[(wr*64 + i*16 + lo)*32 + quad*8];
    #pragma unroll
    for (int t=0;t<4;t++) bg[t] = *(const bf16x8*)&Bs[(wc*64 + t*16 + lo)*32 + quad*8];
    #pragma unroll
    for (int i=0;i<4;i++)
      #pragma unroll
      for (int t=0;t<4;t++)
        acc[i][t] = __builtin_amdgcn_mfma_f32_16x16x32_bf16(af[i], bg[t], acc[i][t], 0, 0, 0);
    __syncthreads();
  }
  #pragma unroll
  for (int i=0;i<4;i++){
    #pragma unroll
    for (int t=0;t<4;t++){
      int col = col0 + wc*64 + t*16 + lo;
      float cs = cst[col];
      #pragma unroll
      for (int r=0;r<4;r++){
        int row = row0 + wr*64 + i*16 + quad*4 + r;   // C/D: col=lane&15, row=quad*4+reg
        if (row < NN){
          u16 o = fb(acc[i][t][r] + cs);
          if (col < HID) Chg[(long)row*HID + col] = o;
          else           Clin[(long)row*HID + col - HID] = o;
        }
      }
    }
  }
}

// ---------------- per-(node,head) attention dots ----------------
__global__ void k_sdot(const u16* __restrict__ hg, const float* __restrict__ attn,
                       float* __restrict__ ssrc, float* __restrict__ sdst){
  int idx = blockIdx.x*256 + threadIdx.x;
  if (idx >= NN*4) return;
  int n = idx >> 2, h = idx & 3;
  const u16* hp = hg + (long)n*HID + h*OO;
  const float* a0 = attn + h*OO;
  const float* a1 = attn + HID + h*OO;
  float ss=0.f, sd=0.f;
  for (int d=0;d<OO;d++){ float v = bf(hp[d]); ss += v*a0[d]; sd += v*a1[d]; }
  ssrc[idx]=ss; sdst[idx]=sd;
}

__global__ void k_q(const float* __restrict__ We, const float* __restrict__ attn,
                    float* __restrict__ q){
  int t = threadIdx.x;
  if (t >= 40) return;
  int k = t >> 2, h = t & 3;
  float s = 0.f;
  for (int d=0; d<OO; d++) s += We[(long)k*HID + h*OO + d] * attn[2*HID + h*OO + d];
  q[k*4+h] = s;
}

__global__ void k_logits(const int* __restrict__ ei, const float* __restrict__ ea,
                         const float* __restrict__ q, const float* __restrict__ at,
                         const float* __restrict__ ssrc, const float* __restrict__ sdst,
                         float* __restrict__ L){
  int idx = blockIdx.x*256 + threadIdx.x;
  if (idx >= EE*4) return;
  int e = idx >> 2, h = idx & 3;
  int s = ei[e], dd = ei[EE+e];
  float se = 0.f;
  #pragma unroll
  for (int k=0;k<10;k++) se += ea[e*12+1+k] * q[k*4+h];
  float v = ssrc[s*4+h] + sdst[dd*4+h] + se + ea[e*12]*at[h];
  L[idx] = (v>0.f)? v : 0.2f*v;
}

__global__ void k_mden(const int* __restrict__ iptr, const int* __restrict__ eid,
                       const float* __restrict__ L, float* __restrict__ m, float* __restrict__ dinv){
  int idx = blockIdx.x*256 + threadIdx.x;
  if (idx >= NN*4) return;
  int n = idx >> 2, h = idx & 3;
  int b = iptr[n], e1 = iptr[n+1];
  float mx = -INFINITY;
  for (int i=b;i<e1;i++) mx = fmaxf(mx, L[eid[i]*4+h]);
  if (b == e1) mx = 0.f;
  float s = 0.f;
  for (int i=b;i<e1;i++) s += expf(L[eid[i]*4+h] - mx);
  m[idx] = mx;
  dinv[idx] = 1.f/(s + 1e-16f);
}

// ---------------- edge gather: NB nodes per block, We bf16 in LDS ----------------
__global__ __launch_bounds__(256) void k_gath(
    const u16* __restrict__ hg, const int* __restrict__ ei,
    const float* __restrict__ ea, const int* __restrict__ iptr,
    const int* __restrict__ eid, const float* __restrict__ L,
    const float* __restrict__ m, const float* __restrict__ dinv,
    const u16* __restrict__ We16, const float* __restrict__ cb,
    u16* __restrict__ lio)
{
  __shared__ u16  sWe[10*HID];   // 20 KB
  __shared__ float scb[HID];     // 4 KB
  int tid = threadIdx.x;
  for (int i=tid;i<10*HID;i+=256) sWe[i] = We16[i];
  for (int i=tid;i<HID;i+=256) scb[i] = cb[i];
  __syncthreads();
  int d0 = blockIdx.x*NB, dend = min(NN, d0+NB);
  for (int d=d0; d<dend; d++){
    float acc[4];
    #pragma unroll
    for (int j=0;j<4;j++) acc[j] = bf(lio[(long)d*HID + tid + j*256]);
    int b0 = iptr[d], en = iptr[d+1];
    float mm[4], dv[4];
    #pragma unroll
    for (int j=0;j<4;j++){ mm[j]=m[d*4+j]; dv[j]=dinv[d*4+j]; }
    for (int i=b0;i<en;i++){
      int e = eid[i], s_ = ei[e];
      float c10[10];
      #pragma unroll
      for (int k=0;k<10;k++) c10[k] = ea[e*12+1+k];
      float w4[4];
      #pragma unroll
      for (int j=0;j<4;j++) w4[j] = expf(L[e*4+j]-mm[j])*dv[j];
      const u16* hgs = hg + (long)s_*HID + tid;
      #pragma unroll
      for (int j=0;j<4;j++){
        int f = tid + j*256;
        float ew = 0.f;
        #pragma unroll
        for (int k=0;k<10;k++) ew += c10[k]*bf(sWe[k*HID+f]);
        acc[j] += w4[j]*(bf(hgs[j*256]) + ew);
      }
    }
    #pragma unroll
    for (int j=0;j<4;j++){
      int f = tid + j*256;
      lio[(long)d*HID+f] = fb(fmaxf(acc[j] + scb[f], 0.f));
    }
  }
}

// ---------------- layer 3 ----------------
__global__ __launch_bounds__(256) void k_n3(
    const u16* __restrict__ in, const float* __restrict__ scale, const float* __restrict__ shift,
    const float* __restrict__ Wg, const float* __restrict__ lw, const float* __restrict__ lb,
    const float* __restrict__ attn,
    float* __restrict__ hg3, float* __restrict__ lin3,
    float* __restrict__ ssrc, float* __restrict__ sdst)
{
  __shared__ float xin[1024];
  __shared__ float red[256];
  int n = blockIdx.x, tid = threadIdx.x;
  for (int k=tid;k<HID;k+=256) xin[k] = bf(in[(long)n*HID+k])*scale[k]+shift[k];
  __syncthreads();
  float p[4] = {0.f,0.f,0.f,0.f};
  for (int k=tid;k<HID;k+=256){
    float xv = xin[k];
    p[0] += xv*Wg[k*2];   p[1] += xv*Wg[k*2+1];
    p[2] += xv*lw[k*2];   p[3] += xv*lw[k*2+1];
  }
  float r[4];
  for (int q=0;q<4;q++){
    red[tid]=p[q]; __syncthreads();
    for (int o=128;o>0;o>>=1){ if(tid<o) red[tid]+=red[tid+o]; __syncthreads(); }
    r[q]=red[0]; __syncthreads();
  }
  if (tid==0){
    hg3[n*2]   = r[0];
    hg3[n*2+1] = r[1];
    lin3[n*2]   = r[2] + lb[0];
    lin3[n*2+1] = r[3] + lb[1];
    ssrc[n] = r[0]*attn[0] + r[1]*attn[1];
    sdst[n] = r[0]*attn[2] + r[1]*attn[3];
  }
}

__global__ void k_logits3(const int* __restrict__ ei, const float* __restrict__ ea,
                          const float* __restrict__ We, const float* __restrict__ attn,
                          const float* __restrict__ at, const float* __restrict__ ssrc,
                          const float* __restrict__ sdst, float* __restrict__ L){
  int e = blockIdx.x*256 + threadIdx.x;
  if (e >= EE) return;
  int s = ei[e], d = ei[EE+e];
  float e0=0.f, e1=0.f;
  #pragma unroll
  for (int k=0;k<10;k++){
    float c = ea[e*12+1+k];
    e0 += c*We[k*2]; e1 += c*We[k*2+1];
  }
  float se = e0*attn[4] + e1*attn[5];
  float v = ssrc[s] + sdst[d] + se + ea[e*12]*at[0];
  L[e] = (v>0.f)? v : 0.2f*v;
}

__global__ void k_mden3(const int* __restrict__ iptr, const int* __restrict__ eid,
                        const float* __restrict__ L, float* __restrict__ m, float* __restrict__ dinv){
  int n = blockIdx.x*256 + threadIdx.x;
  if (n >= NN) return;
  int b = iptr[n], e1 = iptr[n+1];
  float mx = -INFINITY;
  for (int i=b;i<e1;i++) mx = fmaxf(mx, L[eid[i]]);
  if (b == e1) mx = 0.f;
  float s = 0.f;
  for (int i=b;i<e1;i++) s += expf(L[eid[i]] - mx);
  m[n]=mx; dinv[n]=1.f/(s+1e-16f);
}

__global__ void k_gather3(const int* __restrict__ ei, const float* __restrict__ ea,
                          const int* __restrict__ iptr, const int* __restrict__ eid,
                          const float* __restrict__ L, const float* __restrict__ m,
                          const float* __restrict__ dinv, const float* __restrict__ hg3,
                          const float* __restrict__ We, const float* __restrict__ lin3,
                          const float* __restrict__ cb, float* __restrict__ out){
  int n = blockIdx.x*256 + threadIdx.x;
  if (n >= NN) return;
  int b = iptr[n], en = iptr[n+1];
  float a0=0.f, a1=0.f;
  float mn = m[n], dv = dinv[n];
  for (int i=b;i<en;i++){
    int e = eid[i], s_ = ei[e];
    float w = expf(L[e]-mn)*dv;
    float e0=0.f, e1v=0.f;
    #pragma unroll
    for (int k=0;k<10;k++){
      float c = ea[e*12+1+k];
      e0 += c*We[k*2]; e1v += c*We[k*2+1];
    }
    a0 += w*(hg3[s_*2]+e0);
    a1 += w*(hg3[s_*2+1]+e1v);
  }
  out[n*2]   = fmaxf(lin3[n*2]  +a0+cb[0], 0.f);
  out[n*2+1] = fmaxf(lin3[n*2+1]+a1+cb[1], 0.f);
}

extern "C" void kernel_launch(void* const* d_in, const int* in_sizes, int n_in,
                              void* d_out, int out_size, void* d_ws, size_t ws_size,
                              hipStream_t stream){
  const int* ei = (const int*)d_in[1];

  long long sz[64];
  {
    const long long* s64 = (const long long*)(const void*)in_sizes;
    bool is64 = (n_in >= 2) && (in_sizes[0] == 3340000) && (in_sizes[1] == 0)
                && (s64[1] == 200000);
    for (int i=0;i<n_in && i<64;i++) sz[i] = is64 ? s64[i] : (long long)in_sizes[i];
  }

  int IWg[3], IWe[3], IAttn[3], IAt[3], ICb[3], ILw[3], ILb[3], IG[3], IB[3];
  if (n_in > 8 && sz[8] == (long long)HID*HID){ // setup_inputs() dict order
    for (int l=0;l<3;l++){
      IWg[l]=3+l*5; IWe[l]=4+l*5; IAttn[l]=5+l*5; IAt[l]=6+l*5; ICb[l]=7+l*5;
      ILw[l]=18+l*4; ILb[l]=19+l*4; IG[l]=20+l*4; IB[l]=21+l*4;
    }
  } else {
    int idx=3;
    for (int l=0;l<3;l++){
      IWg[l]=idx++; IWe[l]=idx++; IAttn[l]=idx++; IAt[l]=idx++; ICb[l]=idx++;
      ILw[l]=idx++; ILb[l]=idx++; IG[l]=idx++; IB[l]=idx++;
    }
  }
  #define FP(i) ((const float*)d_in[(i)])

  char* ws = (char*)d_ws;
  size_t off = 0;
  auto alloc = [&](size_t bytes)->void*{ void* p = ws + off; off += (bytes + 255) & ~(size_t)255; return p; };
  auto G = [](long n){ return (int)((n+255)/256); };

  u16*   buf0 = (u16*)  alloc((size_t)NN*HID*2);   // hg (bf16)
  u16*   bufA = (u16*)  alloc((size_t)NN*HID*2);   // layer-1 lin/result
  u16*   bufB = (u16*)  alloc((size_t)NN*HID*2);   // layer-2 lin/result
  u16*   xbf  = (u16*)  alloc((size_t)NN*KP1*2);   // layer-1 A (bf16, padded)
  u16*   Wt   = (u16*)  alloc((size_t)2*HID*HID*2);// fused folded weights [2048][K] K-major
  u16*   We16 = (u16*)  alloc((size_t)10*HID*2);
  float* cst  = (float*)alloc(2*HID*4);
  float* L    = (float*)alloc((size_t)EE*4*4);
  float* m    = (float*)alloc((size_t)NN*4*4);
  float* dinv = (float*)alloc((size_t)NN*4*4);
  float* ssrc = (float*)alloc((size_t)NN*4*4);
  float* sdst = (float*)alloc((size_t)NN*4*4);
  int*   iptr = (int*)  alloc((size_t)(NN+4)*4);
  int*   cnts = (int*)  alloc((size_t)NN*4);
  int*   eid  = (int*)  alloc((size_t)EE*4);
  float* stats= (float*)alloc(2*HID*4);
  float* scale= (float*)alloc(HID*4);
  float* shift= (float*)alloc(HID*4);
  float* qbuf = (float*)alloc(64*4);
  float* hg3  = (float*)alloc((size_t)NN*2*4);
  float* lin3 = (float*)alloc((size_t)NN*2*4);

  // ---- CSR by dst ----
  hipMemsetAsync(cnts, 0, NN*sizeof(int), stream);
  k_count<<<G(EE),256,0,stream>>>(ei, cnts);
  k_scan<<<1,256,0,stream>>>(cnts, iptr);
  hipMemsetAsync(cnts, 0, NN*sizeof(int), stream);
  k_fill<<<G(EE),256,0,stream>>>(ei, iptr, cnts, eid);

  dim3 gg(16, 157);   // x = col tiles (2048/128, fast), y = row tiles (ceil(20000/128))

  // ---- layer 1 (A = bf16(x), Kp=192) ----
  {
    hipMemsetAsync(stats, 0, 2*FIN*sizeof(float), stream);
    dim3 bg(200, 1);
    k_bnstats<float><<<bg,256,0,stream>>>(FP(0), stats, FIN);
    k_bnfin<<<1,256,0,stream>>>(stats, FP(IG[0]), FP(IB[0]), scale, shift, FIN);
    k_cast<<<G((long)NN*KP1),256,0,stream>>>(FP(0), xbf);
    dim3 ft(KP1/32, 64);
    k_foldT<<<ft,256,0,stream>>>(FP(IWg[0]), FP(ILw[0]), scale, Wt, FIN, KP1);
    k_cinit<<<8,256,0,stream>>>(FP(ILb[0]), cst);
    dim3 cg(32, (FIN+127)/128);
    k_const<<<cg,256,0,stream>>>(FP(IWg[0]), FP(ILw[0]), shift, cst, FIN);
    k_we16<<<40,256,0,stream>>>(FP(IWe[0]), We16);
    k_gemm<<<gg,256,0,stream>>>(xbf, KP1, Wt, cst, buf0, bufA);
    k_sdot<<<G(NN*4),256,0,stream>>>(buf0, FP(IAttn[0]), ssrc, sdst);
    k_q<<<1,64,0,stream>>>(FP(IWe[0]), FP(IAttn[0]), qbuf);
    k_logits<<<G(EE*4),256,0,stream>>>(ei, FP(2), qbuf, FP(IAt[0]), ssrc, sdst, L);
    k_mden<<<G(NN*4),256,0,stream>>>(iptr, eid, L, m, dinv);
    k_gath<<<(NN+NB-1)/NB,256,0,stream>>>(buf0, ei, FP(2), iptr, eid, L, m, dinv,
                                          We16, FP(ICb[0]), bufA);
  }
  // ---- layer 2 (A = bufA, K=1024) ----
  {
    hipMemsetAsync(stats, 0, 2*HID*sizeof(float), stream);
    dim3 bg(200, 4);
    k_bnstats<u16><<<bg,256,0,stream>>>(bufA, stats, HID);
    k_bnfin<<<4,256,0,stream>>>(stats, FP(IG[1]), FP(IB[1]), scale, shift, HID);
    dim3 ft(HID/32, 64);
    k_foldT<<<ft,256,0,stream>>>(FP(IWg[1]), FP(ILw[1]), scale, Wt, HID, HID);
    k_cinit<<<8,256,0,stream>>>(FP(ILb[1]), cst);
    dim3 cg(32, HID/128);
    k_const<<<cg,256,0,stream>>>(FP(IWg[1]), FP(ILw[1]), shift, cst, HID);
    k_we16<<<40,256,0,stream>>>(FP(IWe[1]), We16);
    k_gemm<<<gg,256,0,stream>>>(bufA, HID, Wt, cst, buf0, bufB);
    k_sdot<<<G(NN*4),256,0,stream>>>(buf0, FP(IAttn[1]), ssrc, sdst);
    k_q<<<1,64,0,stream>>>(FP(IWe[1]), FP(IAttn[1]), qbuf);
    k_logits<<<G(EE*4),256,0,stream>>>(ei, FP(2), qbuf, FP(IAt[1]), ssrc, sdst, L);
    k_mden<<<G(NN*4),256,0,stream>>>(iptr, eid, L, m, dinv);
    k_gath<<<(NN+NB-1)/NB,256,0,stream>>>(buf0, ei, FP(2), iptr, eid, L, m, dinv,
                                          We16, FP(ICb[1]), bufB);
  }

  // ---- layer 3 (input = bufB) ----
  hipMemsetAsync(stats, 0, 2*HID*sizeof(float), stream);
  dim3 bg3(200, 4);
  k_bnstats<u16><<<bg3,256,0,stream>>>(bufB, stats, HID);
  k_bnfin<<<4,256,0,stream>>>(stats, FP(IG[2]), FP(IB[2]), scale, shift, HID);
  k_n3<<<NN,256,0,stream>>>(bufB, scale, shift, FP(IWg[2]), FP(ILw[2]), FP(ILb[2]),
                            FP(IAttn[2]), hg3, lin3, ssrc, sdst);
  k_logits3<<<G(EE),256,0,stream>>>(ei, FP(2), FP(IWe[2]), FP(IAttn[2]), FP(IAt[2]), ssrc, sdst, L);
  k_mden3<<<G(NN),256,0,stream>>>(iptr, eid, L, m, dinv);
  k_gather3<<<G(NN),256,0,stream>>>(ei, FP(2), iptr, eid, L, m, dinv, hg3,
                                    FP(IWe[2]), lin3, FP(ICb[2]), (float*)d_out);
}

// Round 16
// 957.239 us; speedup vs baseline: 1.0180x; 1.0180x over previous
//
#include <hip/hip_runtime.h>
#include <math.h>

#define NN 20000
#define EE 100000
#define FIN 167
#define KP1 192    // layer-1 K padded to mult of 32
#define HID 1024   // H*O = 4*256
#define OO 256
#define NB 16      // nodes per k_gath block

typedef unsigned short u16;
typedef short bf16x8 __attribute__((ext_vector_type(8)));
typedef float f32x4  __attribute__((ext_vector_type(4)));

__device__ __forceinline__ float bf(u16 u){ return __uint_as_float(((unsigned)u)<<16); }
__device__ __forceinline__ u16 fb(float v){            // f32 -> bf16 RNE
  unsigned u = __float_as_uint(v);
  return (u16)((u + 0x7FFFu + ((u>>16)&1u)) >> 16);
}
__device__ __forceinline__ float ldv(const float* p, long i){ return p[i]; }
__device__ __forceinline__ float ldv(const u16*   p, long i){ return bf(p[i]); }

// ---------------- CSR build ----------------
__global__ void k_count(const int* __restrict__ ei, int* __restrict__ counts){
  int e = blockIdx.x*256 + threadIdx.x;
  if (e < EE) atomicAdd(&counts[ei[EE+e]], 1);
}

__global__ __launch_bounds__(256) void k_scan(const int* __restrict__ counts, int* __restrict__ iptr){
  __shared__ int sd[256];
  int tid = threadIdx.x;
  int carry = 0;
  for (int base=0; base<NN; base+=256){
    int i = base+tid;
    int v = (i<NN)? counts[i] : 0;
    sd[tid]=v;
    __syncthreads();
    for (int off=1; off<256; off<<=1){
      int t = (tid>=off)? sd[tid-off] : 0;
      __syncthreads();
      sd[tid] += t;
      __syncthreads();
    }
    if (i<NN) iptr[i] = carry + sd[tid] - v;
    carry += sd[255];
    __syncthreads();
  }
  if (tid==0) iptr[NN]=carry;
}

__global__ void k_fill(const int* __restrict__ ei, const int* __restrict__ iptr,
                       int* __restrict__ cursor, int* __restrict__ eid){
  int e = blockIdx.x*256 + threadIdx.x;
  if (e < EE){
    int d = ei[EE+e];
    int pos = atomicAdd(&cursor[d],1);
    eid[iptr[d]+pos] = e;
  }
}

// ---------------- BatchNorm stats ----------------
template<typename T>
__global__ void k_bnstats(const T* __restrict__ X, float* __restrict__ sums, int F){
  int f = blockIdx.y*256 + threadIdx.x;
  if (f >= F) return;
  int r0 = blockIdx.x*100, r1 = r0+100;
  float s=0.f, s2=0.f;
  for (int r=r0;r<r1;r++){ float v = ldv(X,(long)r*F+f); s += v; s2 += v*v; }
  atomicAdd(&sums[f], s);
  atomicAdd(&sums[F+f], s2);
}

__global__ void k_bnfin(const float* __restrict__ sums, const float* __restrict__ g,
                        const float* __restrict__ b, float* __restrict__ scale,
                        float* __restrict__ shift, int F){
  int f = blockIdx.x*256 + threadIdx.x;
  if (f >= F) return;
  float mu  = sums[f]   * (1.f/NN);
  float var = sums[F+f] * (1.f/NN) - mu*mu;
  float sc  = rsqrtf(var + 1e-5f) * g[f];
  scale[f] = sc;
  shift[f] = b[f] - mu*sc;
}

// ---------------- BN-folded fused weight prep ----------------
__global__ __launch_bounds__(256) void k_foldT(const float* __restrict__ Wg, const float* __restrict__ Wl,
                        const float* __restrict__ scale,
                        u16* __restrict__ Wt, int K, int Kp){
  __shared__ float t[32][33];
  int k0 = blockIdx.x*32, c0 = blockIdx.y*32;
  int tx = threadIdx.x & 31, ty = threadIdx.x >> 5;
  bool second = (c0 >= HID);
  const float* W = second ? Wl : Wg;
  int cc0 = second ? c0 - HID : c0;
  #pragma unroll
  for (int i=0;i<4;i++){
    int k = k0 + ty + i*8;
    t[ty+i*8][tx] = (k < K) ? W[(long)k*HID + cc0 + tx] * scale[k] : 0.f;
  }
  __syncthreads();
  #pragma unroll
  for (int i=0;i<4;i++){
    int c = c0 + ty + i*8;
    Wt[(long)c*Kp + k0 + tx] = fb(t[tx][ty+i*8]);
  }
}

// cst init: lb for lin half, 0 for hg half
__global__ void k_cinit(const float* __restrict__ lb, float* __restrict__ cst){
  int c = blockIdx.x*256 + threadIdx.x;
  if (c < 2*HID) cst[c] = (c >= HID) ? lb[c-HID] : 0.f;
}

// cst[c] += sum_k shift[k]*W[k][c]  — parallel reduction, coalesced
__global__ __launch_bounds__(256) void k_const(const float* __restrict__ Wg, const float* __restrict__ Wl,
                        const float* __restrict__ shift, float* __restrict__ cst, int K){
  int tx = threadIdx.x & 63, ty = threadIdx.x >> 6;
  int c = blockIdx.x*64 + tx;
  bool second = c >= HID;
  const float* W = second ? Wl : Wg;
  int cc = second ? c-HID : c;
  int k0 = blockIdx.y*128;
  int k1 = min(K, k0+128);
  float s = 0.f;
  for (int k=k0+ty; k<k1; k+=4) s += shift[k]*W[(long)k*HID+cc];
  __shared__ float red[256];
  red[threadIdx.x] = s;
  __syncthreads();
  if (ty == 0){
    float tot = red[tx] + red[tx+64] + red[tx+128] + red[tx+192];
    atomicAdd(&cst[c], tot);
  }
}

__global__ void k_cast(const float* __restrict__ x, u16* __restrict__ xb){
  long idx = (long)blockIdx.x*256 + threadIdx.x;
  if (idx >= (long)NN*KP1) return;
  int n = (int)(idx / KP1), k = (int)(idx % KP1);
  xb[idx] = (k<FIN)? fb(x[(long)n*FIN+k]) : (u16)0;
}

__global__ void k_we16(const float* __restrict__ We, u16* __restrict__ We16){
  int i = blockIdx.x*256 + threadIdx.x;
  if (i < 10*HID) We16[i] = fb(We[i]);
}

// ---------------- LDS-tiled MFMA GEMM, XCD-swizzled ----------------
// Tile 128x128, BK=32, global_load_lds staging (2 instrs/wave/buffer).
// Flat grid 2560: b -> xcd=b&7, s=b>>3, rowtile=xcd*20+(s>>4), coltile=s&15.
// All 16 col-tiles of a row-tile run on ONE XCD -> A row-tile fetched once per L2.
__global__ __launch_bounds__(256) void k_gemm(const u16* __restrict__ A, int K,
                     const u16* __restrict__ Wt, const float* __restrict__ cst,
                     u16* __restrict__ Chg, u16* __restrict__ Clin){
  __shared__ u16 As[128*32];   // [row][k] contiguous, 64 B/row
  __shared__ u16 Bs[128*32];
  int b = blockIdx.x;
  int xcd = b & 7, s = b >> 3;
  int row0 = (xcd*20 + (s>>4)) * 128;
  int col0 = (s & 15) * 128;
  int tid = threadIdx.x;
  int wave = tid>>6, lane = tid&63, quad = lane>>4, lo = lane&15;
  int wr = wave>>1, wc = wave&1;
  // staging: wave w covers rows [32w, 32w+32): two instructions, 16 rows each
  int ra0 = wave*32 + (lane>>2);
  int ra1 = ra0 + 16;
  int qa = lane&3;
  int gr0 = row0 + ra0; if (gr0 >= NN) gr0 = NN-1;   // clamp: garbage rows never stored
  int gr1 = row0 + ra1; if (gr1 >= NN) gr1 = NN-1;
  const u16* Agp0 = A  + (long)gr0*K + qa*8;
  const u16* Agp1 = A  + (long)gr1*K + qa*8;
  const u16* Bgp0 = Wt + (long)(col0+ra0)*K + qa*8;
  const u16* Bgp1 = Wt + (long)(col0+ra1)*K + qa*8;
  u16* AsW0 = &As[wave*1024];            // rows 32w..32w+15
  u16* AsW1 = &As[wave*1024 + 512];      // rows 32w+16..32w+31
  u16* BsW0 = &Bs[wave*1024];
  u16* BsW1 = &Bs[wave*1024 + 512];
  f32x4 acc[4][4] = {};
  for (int k0=0;k0<K;k0+=32){
    __builtin_amdgcn_global_load_lds(Agp0 + k0, AsW0, 16, 0, 0);
    __builtin_amdgcn_global_load_lds(Agp1 + k0, AsW1, 16, 0, 0);
    __builtin_amdgcn_global_load_lds(Bgp0 + k0, BsW0, 16, 0, 0);
    __builtin_amdgcn_global_load_lds(Bgp1 + k0, BsW1, 16, 0, 0);
    __syncthreads();   // compiler emits vmcnt(0) drain before barrier
    bf16x8 af[4], bg[4];
    #pragma unroll
    for (int i=0;i<4;i++) af[i] = *(const bf16x8*)&As[(wr*64 + i*16 + lo)*32 + quad*8];
    #pragma unroll
    for (int t=0;t<4;t++) bg[t] = *(const bf16x8*)&Bs[(wc*64 + t*16 + lo)*32 + quad*8];
    #pragma unroll
    for (int i=0;i<4;i++)
      #pragma unroll
      for (int t=0;t<4;t++)
        acc[i][t] = __builtin_amdgcn_mfma_f32_16x16x32_bf16(af[i], bg[t], acc[i][t], 0, 0, 0);
    __syncthreads();
  }
  #pragma unroll
  for (int i=0;i<4;i++){
    #pragma unroll
    for (int t=0;t<4;t++){
      int col = col0 + wc*64 + t*16 + lo;
      float cs = cst[col];
      #pragma unroll
      for (int r=0;r<4;r++){
        int row = row0 + wr*64 + i*16 + quad*4 + r;   // C/D: col=lane&15, row=quad*4+reg
        if (row < NN){
          u16 o = fb(acc[i][t][r] + cs);
          if (col < HID) Chg[(long)row*HID + col] = o;
          else           Clin[(long)row*HID + col - HID] = o;
        }
      }
    }
  }
}

// ---------------- per-(node,head) attention dots ----------------
__global__ void k_sdot(const u16* __restrict__ hg, const float* __restrict__ attn,
                       float* __restrict__ ssrc, float* __restrict__ sdst){
  int idx = blockIdx.x*256 + threadIdx.x;
  if (idx >= NN*4) return;
  int n = idx >> 2, h = idx & 3;
  const u16* hp = hg + (long)n*HID + h*OO;
  const float* a0 = attn + h*OO;
  const float* a1 = attn + HID + h*OO;
  float ss=0.f, sd=0.f;
  for (int d=0;d<OO;d++){ float v = bf(hp[d]); ss += v*a0[d]; sd += v*a1[d]; }
  ssrc[idx]=ss; sdst[idx]=sd;
}

__global__ void k_q(const float* __restrict__ We, const float* __restrict__ attn,
                    float* __restrict__ q){
  int t = threadIdx.x;
  if (t >= 40) return;
  int k = t >> 2, h = t & 3;
  float s = 0.f;
  for (int d=0; d<OO; d++) s += We[(long)k*HID + h*OO + d] * attn[2*HID + h*OO + d];
  q[k*4+h] = s;
}

__global__ void k_logits(const int* __restrict__ ei, const float* __restrict__ ea,
                         const float* __restrict__ q, const float* __restrict__ at,
                         const float* __restrict__ ssrc, const float* __restrict__ sdst,
                         float* __restrict__ L){
  int idx = blockIdx.x*256 + threadIdx.x;
  if (idx >= EE*4) return;
  int e = idx >> 2, h = idx & 3;
  int s = ei[e], dd = ei[EE+e];
  float se = 0.f;
  #pragma unroll
  for (int k=0;k<10;k++) se += ea[e*12+1+k] * q[k*4+h];
  float v = ssrc[s*4+h] + sdst[dd*4+h] + se + ea[e*12]*at[h];
  L[idx] = (v>0.f)? v : 0.2f*v;
}

__global__ void k_mden(const int* __restrict__ iptr, const int* __restrict__ eid,
                       const float* __restrict__ L, float* __restrict__ m, float* __restrict__ dinv){
  int idx = blockIdx.x*256 + threadIdx.x;
  if (idx >= NN*4) return;
  int n = idx >> 2, h = idx & 3;
  int b = iptr[n], e1 = iptr[n+1];
  float mx = -INFINITY;
  for (int i=b;i<e1;i++) mx = fmaxf(mx, L[eid[i]*4+h]);
  if (b == e1) mx = 0.f;
  float s = 0.f;
  for (int i=b;i<e1;i++) s += expf(L[eid[i]*4+h] - mx);
  m[idx] = mx;
  dinv[idx] = 1.f/(s + 1e-16f);
}

// ---------------- edge gather: NB nodes per block, We bf16 in LDS ----------------
__global__ __launch_bounds__(256) void k_gath(
    const u16* __restrict__ hg, const int* __restrict__ ei,
    const float* __restrict__ ea, const int* __restrict__ iptr,
    const int* __restrict__ eid, const float* __restrict__ L,
    const float* __restrict__ m, const float* __restrict__ dinv,
    const u16* __restrict__ We16, const float* __restrict__ cb,
    u16* __restrict__ lio)
{
  __shared__ u16  sWe[10*HID];   // 20 KB
  __shared__ float scb[HID];     // 4 KB
  int tid = threadIdx.x;
  for (int i=tid;i<10*HID;i+=256) sWe[i] = We16[i];
  for (int i=tid;i<HID;i+=256) scb[i] = cb[i];
  __syncthreads();
  int d0 = blockIdx.x*NB, dend = min(NN, d0+NB);
  for (int d=d0; d<dend; d++){
    float acc[4];
    #pragma unroll
    for (int j=0;j<4;j++) acc[j] = bf(lio[(long)d*HID + tid + j*256]);
    int b0 = iptr[d], en = iptr[d+1];
    float mm[4], dv[4];
    #pragma unroll
    for (int j=0;j<4;j++){ mm[j]=m[d*4+j]; dv[j]=dinv[d*4+j]; }
    for (int i=b0;i<en;i++){
      int e = eid[i], s_ = ei[e];
      float c10[10];
      #pragma unroll
      for (int k=0;k<10;k++) c10[k] = ea[e*12+1+k];
      float w4[4];
      #pragma unroll
      for (int j=0;j<4;j++) w4[j] = expf(L[e*4+j]-mm[j])*dv[j];
      const u16* hgs = hg + (long)s_*HID + tid;
      #pragma unroll
      for (int j=0;j<4;j++){
        int f = tid + j*256;
        float ew = 0.f;
        #pragma unroll
        for (int k=0;k<10;k++) ew += c10[k]*bf(sWe[k*HID+f]);
        acc[j] += w4[j]*(bf(hgs[j*256]) + ew);
      }
    }
    #pragma unroll
    for (int j=0;j<4;j++){
      int f = tid + j*256;
      lio[(long)d*HID+f] = fb(fmaxf(acc[j] + scb[f], 0.f));
    }
  }
}

// ---------------- layer 3 ----------------
__global__ __launch_bounds__(256) void k_n3(
    const u16* __restrict__ in, const float* __restrict__ scale, const float* __restrict__ shift,
    const float* __restrict__ Wg, const float* __restrict__ lw, const float* __restrict__ lb,
    const float* __restrict__ attn,
    float* __restrict__ hg3, float* __restrict__ lin3,
    float* __restrict__ ssrc, float* __restrict__ sdst)
{
  __shared__ float xin[1024];
  __shared__ float red[256];
  int n = blockIdx.x, tid = threadIdx.x;
  for (int k=tid;k<HID;k+=256) xin[k] = bf(in[(long)n*HID+k])*scale[k]+shift[k];
  __syncthreads();
  float p[4] = {0.f,0.f,0.f,0.f};
  for (int k=tid;k<HID;k+=256){
    float xv = xin[k];
    p[0] += xv*Wg[k*2];   p[1] += xv*Wg[k*2+1];
    p[2] += xv*lw[k*2];   p[3] += xv*lw[k*2+1];
  }
  float r[4];
  for (int q=0;q<4;q++){
    red[tid]=p[q]; __syncthreads();
    for (int o=128;o>0;o>>=1){ if(tid<o) red[tid]+=red[tid+o]; __syncthreads(); }
    r[q]=red[0]; __syncthreads();
  }
  if (tid==0){
    hg3[n*2]   = r[0];
    hg3[n*2+1] = r[1];
    lin3[n*2]   = r[2] + lb[0];
    lin3[n*2+1] = r[3] + lb[1];
    ssrc[n] = r[0]*attn[0] + r[1]*attn[1];
    sdst[n] = r[0]*attn[2] + r[1]*attn[3];
  }
}

__global__ void k_logits3(const int* __restrict__ ei, const float* __restrict__ ea,
                          const float* __restrict__ We, const float* __restrict__ attn,
                          const float* __restrict__ at, const float* __restrict__ ssrc,
                          const float* __restrict__ sdst, float* __restrict__ L){
  int e = blockIdx.x*256 + threadIdx.x;
  if (e >= EE) return;
  int s = ei[e], d = ei[EE+e];
  float e0=0.f, e1=0.f;
  #pragma unroll
  for (int k=0;k<10;k++){
    float c = ea[e*12+1+k];
    e0 += c*We[k*2]; e1 += c*We[k*2+1];
  }
  float se = e0*attn[4] + e1*attn[5];
  float v = ssrc[s] + sdst[d] + se + ea[e*12]*at[0];
  L[e] = (v>0.f)? v : 0.2f*v;
}

__global__ void k_mden3(const int* __restrict__ iptr, const int* __restrict__ eid,
                        const float* __restrict__ L, float* __restrict__ m, float* __restrict__ dinv){
  int n = blockIdx.x*256 + threadIdx.x;
  if (n >= NN) return;
  int b = iptr[n], e1 = iptr[n+1];
  float mx = -INFINITY;
  for (int i=b;i<e1;i++) mx = fmaxf(mx, L[eid[i]]);
  if (b == e1) mx = 0.f;
  float s = 0.f;
  for (int i=b;i<e1;i++) s += expf(L[eid[i]] - mx);
  m[n]=mx; dinv[n]=1.f/(s+1e-16f);
}

__global__ void k_gather3(const int* __restrict__ ei, const float* __restrict__ ea,
                          const int* __restrict__ iptr, const int* __restrict__ eid,
                          const float* __restrict__ L, const float* __restrict__ m,
                          const float* __restrict__ dinv, const float* __restrict__ hg3,
                          const float* __restrict__ We, const float* __restrict__ lin3,
                          const float* __restrict__ cb, float* __restrict__ out){
  int n = blockIdx.x*256 + threadIdx.x;
  if (n >= NN) return;
  int b = iptr[n], en = iptr[n+1];
  float a0=0.f, a1=0.f;
  float mn = m[n], dv = dinv[n];
  for (int i=b;i<en;i++){
    int e = eid[i], s_ = ei[e];
    float w = expf(L[e]-mn)*dv;
    float e0=0.f, e1v=0.f;
    #pragma unroll
    for (int k=0;k<10;k++){
      float c = ea[e*12+1+k];
      e0 += c*We[k*2]; e1v += c*We[k*2+1];
    }
    a0 += w*(hg3[s_*2]+e0);
    a1 += w*(hg3[s_*2+1]+e1v);
  }
  out[n*2]   = fmaxf(lin3[n*2]  +a0+cb[0], 0.f);
  out[n*2+1] = fmaxf(lin3[n*2+1]+a1+cb[1], 0.f);
}

extern "C" void kernel_launch(void* const* d_in, const int* in_sizes, int n_in,
                              void* d_out, int out_size, void* d_ws, size_t ws_size,
                              hipStream_t stream){
  const int* ei = (const int*)d_in[1];

  long long sz[64];
  {
    const long long* s64 = (const long long*)(const void*)in_sizes;
    bool is64 = (n_in >= 2) && (in_sizes[0] == 3340000) && (in_sizes[1] == 0)
                && (s64[1] == 200000);
    for (int i=0;i<n_in && i<64;i++) sz[i] = is64 ? s64[i] : (long long)in_sizes[i];
  }

  int IWg[3], IWe[3], IAttn[3], IAt[3], ICb[3], ILw[3], ILb[3], IG[3], IB[3];
  if (n_in > 8 && sz[8] == (long long)HID*HID){ // setup_inputs() dict order
    for (int l=0;l<3;l++){
      IWg[l]=3+l*5; IWe[l]=4+l*5; IAttn[l]=5+l*5; IAt[l]=6+l*5; ICb[l]=7+l*5;
      ILw[l]=18+l*4; ILb[l]=19+l*4; IG[l]=20+l*4; IB[l]=21+l*4;
    }
  } else {
    int idx=3;
    for (int l=0;l<3;l++){
      IWg[l]=idx++; IWe[l]=idx++; IAttn[l]=idx++; IAt[l]=idx++; ICb[l]=idx++;
      ILw[l]=idx++; ILb[l]=idx++; IG[l]=idx++; IB[l]=idx++;
    }
  }
  #define FP(i) ((const float*)d_in[(i)])

  char* ws = (char*)d_ws;
  size_t off = 0;
  auto alloc = [&](size_t bytes)->void*{ void* p = ws + off; off += (bytes + 255) & ~(size_t)255; return p; };
  auto G = [](long n){ return (int)((n+255)/256); };

  u16*   buf0 = (u16*)  alloc((size_t)NN*HID*2);   // hg (bf16)
  u16*   bufA = (u16*)  alloc((size_t)NN*HID*2);   // layer-1 lin/result
  u16*   bufB = (u16*)  alloc((size_t)NN*HID*2);   // layer-2 lin/result
  u16*   xbf  = (u16*)  alloc((size_t)NN*KP1*2);   // layer-1 A (bf16, padded)
  u16*   Wt   = (u16*)  alloc((size_t)2*HID*HID*2);// fused folded weights [2048][K] K-major
  u16*   We16 = (u16*)  alloc((size_t)10*HID*2);
  float* cst  = (float*)alloc(2*HID*4);
  float* L    = (float*)alloc((size_t)EE*4*4);
  float* m    = (float*)alloc((size_t)NN*4*4);
  float* dinv = (float*)alloc((size_t)NN*4*4);
  float* ssrc = (float*)alloc((size_t)NN*4*4);
  float* sdst = (float*)alloc((size_t)NN*4*4);
  int*   iptr = (int*)  alloc((size_t)(NN+4)*4);
  int*   cnts = (int*)  alloc((size_t)NN*4);
  int*   eid  = (int*)  alloc((size_t)EE*4);
  float* stats= (float*)alloc(2*HID*4);
  float* scale= (float*)alloc(HID*4);
  float* shift= (float*)alloc(HID*4);
  float* qbuf = (float*)alloc(64*4);
  float* hg3  = (float*)alloc((size_t)NN*2*4);
  float* lin3 = (float*)alloc((size_t)NN*2*4);

  // ---- CSR by dst ----
  hipMemsetAsync(cnts, 0, NN*sizeof(int), stream);
  k_count<<<G(EE),256,0,stream>>>(ei, cnts);
  k_scan<<<1,256,0,stream>>>(cnts, iptr);
  hipMemsetAsync(cnts, 0, NN*sizeof(int), stream);
  k_fill<<<G(EE),256,0,stream>>>(ei, iptr, cnts, eid);

  int gg = 2560;   // flat, XCD-swizzled in-kernel (160 row tiles x 16 col tiles)

  // ---- layer 1 (A = bf16(x), Kp=192) ----
  {
    hipMemsetAsync(stats, 0, 2*FIN*sizeof(float), stream);
    dim3 bg(200, 1);
    k_bnstats<float><<<bg,256,0,stream>>>(FP(0), stats, FIN);
    k_bnfin<<<1,256,0,stream>>>(stats, FP(IG[0]), FP(IB[0]), scale, shift, FIN);
    k_cast<<<G((long)NN*KP1),256,0,stream>>>(FP(0), xbf);
    dim3 ft(KP1/32, 64);
    k_foldT<<<ft,256,0,stream>>>(FP(IWg[0]), FP(ILw[0]), scale, Wt, FIN, KP1);
    k_cinit<<<8,256,0,stream>>>(FP(ILb[0]), cst);
    dim3 cg(32, (FIN+127)/128);
    k_const<<<cg,256,0,stream>>>(FP(IWg[0]), FP(ILw[0]), shift, cst, FIN);
    k_we16<<<40,256,0,stream>>>(FP(IWe[0]), We16);
    k_gemm<<<gg,256,0,stream>>>(xbf, KP1, Wt, cst, buf0, bufA);
    k_sdot<<<G(NN*4),256,0,stream>>>(buf0, FP(IAttn[0]), ssrc, sdst);
    k_q<<<1,64,0,stream>>>(FP(IWe[0]), FP(IAttn[0]), qbuf);
    k_logits<<<G(EE*4),256,0,stream>>>(ei, FP(2), qbuf, FP(IAt[0]), ssrc, sdst, L);
    k_mden<<<G(NN*4),256,0,stream>>>(iptr, eid, L, m, dinv);
    k_gath<<<(NN+NB-1)/NB,256,0,stream>>>(buf0, ei, FP(2), iptr, eid, L, m, dinv,
                                          We16, FP(ICb[0]), bufA);
  }
  // ---- layer 2 (A = bufA, K=1024) ----
  {
    hipMemsetAsync(stats, 0, 2*HID*sizeof(float), stream);
    dim3 bg(200, 4);
    k_bnstats<u16><<<bg,256,0,stream>>>(bufA, stats, HID);
    k_bnfin<<<4,256,0,stream>>>(stats, FP(IG[1]), FP(IB[1]), scale, shift, HID);
    dim3 ft(HID/32, 64);
    k_foldT<<<ft,256,0,stream>>>(FP(IWg[1]), FP(ILw[1]), scale, Wt, HID, HID);
    k_cinit<<<8,256,0,stream>>>(FP(ILb[1]), cst);
    dim3 cg(32, HID/128);
    k_const<<<cg,256,0,stream>>>(FP(IWg[1]), FP(ILw[1]), shift, cst, HID);
    k_we16<<<40,256,0,stream>>>(FP(IWe[1]), We16);
    k_gemm<<<gg,256,0,stream>>>(bufA, HID, Wt, cst, buf0, bufB);
    k_sdot<<<G(NN*4),256,0,stream>>>(buf0, FP(IAttn[1]), ssrc, sdst);
    k_q<<<1,64,0,stream>>>(FP(IWe[1]), FP(IAttn[1]), qbuf);
    k_logits<<<G(EE*4),256,0,stream>>>(ei, FP(2), qbuf, FP(IAt[1]), ssrc, sdst, L);
    k_mden<<<G(NN*4),256,0,stream>>>(iptr, eid, L, m, dinv);
    k_gath<<<(NN+NB-1)/NB,256,0,stream>>>(buf0, ei, FP(2), iptr, eid, L, m, dinv,
                                          We16, FP(ICb[1]), bufB);
  }

  // ---- layer 3 (input = bufB) ----
  hipMemsetAsync(stats, 0, 2*HID*sizeof(float), stream);
  dim3 bg3(200, 4);
  k_bnstats<u16><<<bg3,256,0,stream>>>(bufB, stats, HID);
  k_bnfin<<<4,256,0,stream>>>(stats, FP(IG[2]), FP(IB[2]), scale, shift, HID);
  k_n3<<<NN,256,0,stream>>>(bufB, scale, shift, FP(IWg[2]), FP(ILw[2]), FP(ILb[2]),
                            FP(IAttn[2]), hg3, lin3, ssrc, sdst);
  k_logits3<<<G(EE),256,0,stream>>>(ei, FP(2), FP(IWe[2]), FP(IAttn[2]), FP(IAt[2]), ssrc, sdst, L);
  k_mden3<<<G(NN),256,0,stream>>>(iptr, eid, L, m, dinv);
  k_gather3<<<G(NN),256,0,stream>>>(ei, FP(2), iptr, eid, L, m, dinv, hg3,
                                    FP(IWe[2]), lin3, FP(ICb[2]), (float*)d_out);
}